// Round 1
// baseline (190.148 us; speedup 1.0000x reference)
//
#include <hip/hip_runtime.h>
#include <math.h>

#define Hh 512
#define Ww 512
#define Bb 4
#define Ee 32
#define PLANE (Hh*Ww)        // 262144
#define NOFF 9

// ws layout (float indices)
#define WS_BLUR   0          // 262144 floats: blurred raw
#define WS_TMP    262144     // 262144 floats: H-blur intermediate
#define WS_KW     524288     // 16 floats: gaussian weights (11 used)
#define WS_MIN    524304     // 16 uints: per-offset min bits
#define WS_MAX    524320     // 16 uints: per-offset max bits
#define WS_ACC    524336     // double accumulator (byte 2097344, 8-aligned)

__device__ __constant__ int d_OH[NOFF] = {0,-1,-1,0,-2,-2,0,-3,-3};
__device__ __constant__ int d_OW[NOFF] = {-1,0,-1,-2,0,-2,-3,0,-3};

__global__ void k_init(float* ws){
    int t = threadIdx.x;
    unsigned int* mn = (unsigned int*)(ws + WS_MIN);
    unsigned int* mx = (unsigned int*)(ws + WS_MAX);
    if (t < 16){ mn[t] = 0x7F800000u; mx[t] = 0u; }
    if (t == 0){
        *(double*)(ws + WS_ACC) = 0.0;
        // gaussian kernel, sigma=1.2, radius=int(4*1.2+0.5)=5, fp64 like numpy
        double k[11], s = 0.0;
        for (int i = 0; i < 11; i++){
            double x = (double)(i - 5) / 1.2;
            k[i] = exp(-0.5 * x * x);
            s += k[i];
        }
        for (int i = 0; i < 11; i++) ws[WS_KW + i] = (float)(k[i] / s);
    }
}

// blur along H (axis 1), edge-clamped ('nearest')
__global__ void k_blur_h(const float* __restrict__ raw, float* __restrict__ ws){
    int idx = blockIdx.x * 256 + threadIdx.x;   // 0..262143
    int h = idx >> 9, w = idx & 511;
    float acc = 0.f;
    #pragma unroll
    for (int i = 0; i < 11; i++){
        int hh = h + i - 5;
        hh = hh < 0 ? 0 : (hh > Hh-1 ? Hh-1 : hh);
        acc += ws[WS_KW + i] * raw[hh * Ww + w];
    }
    ws[WS_TMP + idx] = acc;
}

// blur along W (axis 2), edge-clamped
__global__ void k_blur_w(float* __restrict__ ws){
    int idx = blockIdx.x * 256 + threadIdx.x;
    int h = idx >> 9, w = idx & 511;
    float acc = 0.f;
    #pragma unroll
    for (int i = 0; i < 11; i++){
        int wwi = w + i - 5;
        wwi = wwi < 0 ? 0 : (wwi > Ww-1 ? Ww-1 : wwi);
        acc += ws[WS_KW + i] * ws[WS_TMP + h * Ww + wwi];
    }
    ws[WS_BLUR + idx] = acc;
}

// per-offset min/max of d_i = |blur - rolled blur| (wrap indexing, matches jnp.roll)
__global__ void k_minmax(float* __restrict__ ws){
    int idx = blockIdx.x * 512 + threadIdx.x;
    int h = idx >> 9, w = idx & 511;
    float bc = ws[WS_BLUR + idx];
    int lane = threadIdx.x & 63, wv = threadIdx.x >> 6;
    __shared__ float smn[8 * NOFF], smx[8 * NOFF];
    #pragma unroll
    for (int i = 0; i < NOFF; i++){
        int hn = (h + d_OH[i]) & (Hh-1);
        int wn = (w + d_OW[i]) & (Ww-1);
        float d = fabsf(bc - ws[WS_BLUR + hn * Ww + wn]);
        float mnv = d, mxv = d;
        for (int s = 32; s; s >>= 1){
            mnv = fminf(mnv, __shfl_xor(mnv, s));
            mxv = fmaxf(mxv, __shfl_xor(mxv, s));
        }
        if (lane == 0){ smn[wv * NOFF + i] = mnv; smx[wv * NOFF + i] = mxv; }
    }
    __syncthreads();
    if (threadIdx.x < NOFF){
        float mnv = smn[threadIdx.x], mxv = smx[threadIdx.x];
        for (int v = 1; v < 8; v++){
            mnv = fminf(mnv, smn[v * NOFF + threadIdx.x]);
            mxv = fmaxf(mxv, smx[v * NOFF + threadIdx.x]);
        }
        // d >= 0, so IEEE float ordering == unsigned-bits ordering
        atomicMin((unsigned int*)(ws + WS_MIN) + threadIdx.x, __float_as_uint(mnv));
        atomicMax((unsigned int*)(ws + WS_MAX) + threadIdx.x, __float_as_uint(mxv));
    }
}

// fused loss: per (b,h,w) thread, 9 dot products over E=32 channels
__launch_bounds__(512)
__global__ void k_main(const float* __restrict__ embeds, const float* __restrict__ tf,
                       const float* __restrict__ mask, float* __restrict__ ws){
    int bh = blockIdx.x;                 // 0..2047 = b*512 + h
    int b = bh >> 9, h = bh & 511;
    int w = threadIdx.x;                 // 0..511
    int pix = h * Ww + w;

    float bc = ws[WS_BLUR + pix];
    const unsigned int* mnb = (const unsigned int*)(ws + WS_MIN);
    const unsigned int* mxb = (const unsigned int*)(ws + WS_MAX);

    float c[NOFF];
    int roff[NOFF];
    #pragma unroll
    for (int i = 0; i < NOFF; i++){
        int hn = (h + d_OH[i]) & (Hh-1);
        int wn = (w + d_OW[i]) & (Ww-1);
        roff[i] = hn * Ww + wn;
        float d = fabsf(bc - ws[WS_BLUR + roff[i]]);
        float mn = __uint_as_float(mnb[i]);
        float mx = __uint_as_float(mxb[i]);
        float a = (d - mn) / (mx - mn);
        c[i] = mask[i * PLANE + pix] * (0.5f - a);
    }

    float dot[NOFF];
    #pragma unroll
    for (int i = 0; i < NOFF; i++) dot[i] = 0.f;

    const float* eb = embeds + (size_t)b * Ee * PLANE + pix;
    const float* tb = tf + (size_t)b * Ee * PLANE;
    #pragma unroll 4
    for (int e = 0; e < Ee; e++){
        float ev = eb[(size_t)e * PLANE];
        const float* tp = tb + (size_t)e * PLANE;
        #pragma unroll
        for (int i = 0; i < NOFF; i++)
            dot[i] = fmaf(ev, tp[roff[i]], dot[i]);
    }

    float part = 0.f;
    #pragma unroll
    for (int i = 0; i < NOFF; i++) part += (1.f - dot[i]) * c[i];

    // block reduction: wave shfl, then LDS across 8 waves
    for (int s = 32; s; s >>= 1) part += __shfl_xor(part, s);
    __shared__ float sp[8];
    int lane = threadIdx.x & 63, wv = threadIdx.x >> 6;
    if (lane == 0) sp[wv] = part;
    __syncthreads();
    if (threadIdx.x == 0){
        float bs = 0.f;
        for (int v = 0; v < 8; v++) bs += sp[v];
        atomicAdd((double*)(ws + WS_ACC), (double)bs);
    }
}

__global__ void k_final(const float* __restrict__ ws, float* __restrict__ out){
    out[0] = (float)(*(const double*)(ws + WS_ACC) / (double)((size_t)Bb * PLANE));
}

extern "C" void kernel_launch(void* const* d_in, const int* in_sizes, int n_in,
                              void* d_out, int out_size, void* d_ws, size_t ws_size,
                              hipStream_t stream) {
    const float* embeds = (const float*)d_in[0];   // [4,32,512,512]
    const float* tf     = (const float*)d_in[1];   // [4,32,512,512]
    const float* raw    = (const float*)d_in[2];   // [1,1,512,512]
    const float* mask   = (const float*)d_in[3];   // [1,9,512,512]
    float* ws  = (float*)d_ws;
    float* out = (float*)d_out;

    k_init  <<<1, 64, 0, stream>>>(ws);
    k_blur_h<<<PLANE/256, 256, 0, stream>>>(raw, ws);
    k_blur_w<<<PLANE/256, 256, 0, stream>>>(ws);
    k_minmax<<<PLANE/512, 512, 0, stream>>>(ws);
    k_main  <<<Bb*Hh, 512, 0, stream>>>(embeds, tf, mask, ws);
    k_final <<<1, 1, 0, stream>>>(ws, out);
}

// Round 2
// 92.013 us; speedup vs baseline: 2.0665x; 2.0665x over previous
//
#include <hip/hip_runtime.h>
#include <math.h>

#define Hh 512
#define Ww 512
#define Bb 4
#define Ee 32
#define PLANE (Hh*Ww)        // 262144
#define NOFF 9

// ws layout (float indices)
#define WS_BLUR   0          // 262144 floats: blurred raw
#define WS_TMP    262144     // 262144 floats: H-blur intermediate
#define WS_KW     524288     // 16 floats: gaussian weights (11 used)
#define WS_MIN    524304     // 16 uints: per-offset min bits
#define WS_MAX    524320     // 16 uints: per-offset max bits
#define WS_ACC    524336     // double accumulator (byte 2097344, 8-aligned)

__global__ void k_init(float* ws){
    int t = threadIdx.x;
    unsigned int* mn = (unsigned int*)(ws + WS_MIN);
    unsigned int* mx = (unsigned int*)(ws + WS_MAX);
    if (t < 16){ mn[t] = 0x7F800000u; mx[t] = 0u; }
    if (t == 0){
        *(double*)(ws + WS_ACC) = 0.0;
        double k[11], s = 0.0;
        for (int i = 0; i < 11; i++){
            double x = (double)(i - 5) / 1.2;
            k[i] = exp(-0.5 * x * x);
            s += k[i];
        }
        for (int i = 0; i < 11; i++) ws[WS_KW + i] = (float)(k[i] / s);
    }
}

// blur along H (axis 1), edge-clamped ('nearest')
__global__ void k_blur_h(const float* __restrict__ raw, float* __restrict__ ws){
    int idx = blockIdx.x * 256 + threadIdx.x;
    int h = idx >> 9, w = idx & 511;
    float acc = 0.f;
    #pragma unroll
    for (int i = 0; i < 11; i++){
        int hh = h + i - 5;
        hh = hh < 0 ? 0 : (hh > Hh-1 ? Hh-1 : hh);
        acc += ws[WS_KW + i] * raw[hh * Ww + w];
    }
    ws[WS_TMP + idx] = acc;
}

// blur along W (axis 2), edge-clamped
__global__ void k_blur_w(float* __restrict__ ws){
    int idx = blockIdx.x * 256 + threadIdx.x;
    int h = idx >> 9, w = idx & 511;
    float acc = 0.f;
    #pragma unroll
    for (int i = 0; i < 11; i++){
        int wwi = w + i - 5;
        wwi = wwi < 0 ? 0 : (wwi > Ww-1 ? Ww-1 : wwi);
        acc += ws[WS_KW + i] * ws[WS_TMP + h * Ww + wwi];
    }
    ws[WS_BLUR + idx] = acc;
}

__device__ __constant__ int d_OH[NOFF] = {0,-1,-1,0,-2,-2,0,-3,-3};
__device__ __constant__ int d_OW[NOFF] = {-1,0,-1,-2,0,-2,-3,0,-3};

// per-offset min/max of d_i = |blur - rolled blur|
__global__ void k_minmax(float* __restrict__ ws){
    int idx = blockIdx.x * 512 + threadIdx.x;
    int h = idx >> 9, w = idx & 511;
    float bc = ws[WS_BLUR + idx];
    int lane = threadIdx.x & 63, wv = threadIdx.x >> 6;
    __shared__ float smn[8 * NOFF], smx[8 * NOFF];
    #pragma unroll
    for (int i = 0; i < NOFF; i++){
        int hn = (h + d_OH[i]) & (Hh-1);
        int wn = (w + d_OW[i]) & (Ww-1);
        float d = fabsf(bc - ws[WS_BLUR + hn * Ww + wn]);
        float mnv = d, mxv = d;
        for (int s = 32; s; s >>= 1){
            mnv = fminf(mnv, __shfl_xor(mnv, s));
            mxv = fmaxf(mxv, __shfl_xor(mxv, s));
        }
        if (lane == 0){ smn[wv * NOFF + i] = mnv; smx[wv * NOFF + i] = mxv; }
    }
    __syncthreads();
    if (threadIdx.x < NOFF){
        float mnv = smn[threadIdx.x], mxv = smx[threadIdx.x];
        for (int v = 1; v < 8; v++){
            mnv = fminf(mnv, smn[v * NOFF + threadIdx.x]);
            mxv = fmaxf(mxv, smx[v * NOFF + threadIdx.x]);
        }
        atomicMin((unsigned int*)(ws + WS_MIN) + threadIdx.x, __float_as_uint(mnv));
        atomicMax((unsigned int*)(ws + WS_MAX) + threadIdx.x, __float_as_uint(mxv));
    }
}

// fused loss: each thread owns 4 consecutive pixels (float4-aligned).
// per px: sum_i c_i(1-dot_i) = csum - sum_e E[e]*(sum_i c_i*T[e,nbr_i])
__launch_bounds__(512)
__global__ void k_main(const float* __restrict__ E, const float* __restrict__ T,
                       const float* __restrict__ mask, float* __restrict__ ws){
    int g = blockIdx.x * 512 + threadIdx.x;   // 0..262143
    int b  = g >> 16;                          // 65536 threads per batch
    int hr = (g >> 7) & 511;                   // row
    int wq = g & 127;                          // quarter-row index
    int c0 = wq << 2;                          // col base (float4-aligned)
    int cl = (c0 - 4) & 511;                   // wrapped left float4 base
    int rr0 = hr, rr1 = (hr-1)&511, rr2 = (hr-2)&511, rr3 = (hr-3)&511;
    int pix = hr * Ww + c0;

    int ro[4] = { rr0*Ww + c0, rr1*Ww + c0, rr2*Ww + c0, rr3*Ww + c0 };
    int lo[4] = { rr0*Ww + cl, rr1*Ww + cl, rr2*Ww + cl, rr3*Ww + cl };

    // ---- blur neighborhood -> per-pixel coefficients c[j][i]
    const float* bl = ws + WS_BLUR;
    float tb[4][8];
    #pragma unroll
    for (int r = 0; r < 4; r++){
        float4 l4 = *(const float4*)(bl + lo[r]);
        float4 o4 = *(const float4*)(bl + ro[r]);
        tb[r][0]=l4.x; tb[r][1]=l4.y; tb[r][2]=l4.z; tb[r][3]=l4.w;
        tb[r][4]=o4.x; tb[r][5]=o4.y; tb[r][6]=o4.z; tb[r][7]=o4.w;
    }
    const unsigned int* mnb = (const unsigned int*)(ws + WS_MIN);
    const unsigned int* mxb = (const unsigned int*)(ws + WS_MAX);
    float mn[NOFF], inv[NOFF];
    #pragma unroll
    for (int i = 0; i < NOFF; i++){
        mn[i]  = __uint_as_float(mnb[i]);
        inv[i] = 1.f / (__uint_as_float(mxb[i]) - mn[i]);
    }
    float mk[NOFF][4];
    #pragma unroll
    for (int i = 0; i < NOFF; i++){
        float4 m4 = *(const float4*)(mask + i * PLANE + pix);
        mk[i][0]=m4.x; mk[i][1]=m4.y; mk[i][2]=m4.z; mk[i][3]=m4.w;
    }
    float c[4][NOFF], csum[4];
    #pragma unroll
    for (int j = 0; j < 4; j++){
        float bc = tb[0][4+j];
        float d[NOFF];
        d[0] = fabsf(bc - tb[0][3+j]);   // ( 0,-1)
        d[1] = fabsf(bc - tb[1][4+j]);   // (-1, 0)
        d[2] = fabsf(bc - tb[1][3+j]);   // (-1,-1)
        d[3] = fabsf(bc - tb[0][2+j]);   // ( 0,-2)
        d[4] = fabsf(bc - tb[2][4+j]);   // (-2, 0)
        d[5] = fabsf(bc - tb[2][2+j]);   // (-2,-2)
        d[6] = fabsf(bc - tb[0][1+j]);   // ( 0,-3)
        d[7] = fabsf(bc - tb[3][4+j]);   // (-3, 0)
        d[8] = fabsf(bc - tb[3][1+j]);   // (-3,-3)
        csum[j] = 0.f;
        #pragma unroll
        for (int i = 0; i < NOFF; i++){
            float a = (d[i] - mn[i]) * inv[i];
            c[j][i] = mk[i][j] * (0.5f - a);
            csum[j] += c[j][i];
        }
    }

    // ---- e-loop: 9 dwordx4 loads per iteration
    const float* Eb = E + (size_t)b * Ee * PLANE + pix;
    const float* Tb = T + (size_t)b * Ee * PLANE;
    float acc[4] = {0.f, 0.f, 0.f, 0.f};
    for (int e = 0; e < Ee; e++){
        const float* Tp = Tb + (size_t)e * PLANE;
        float4 ev4 = *(const float4*)(Eb + (size_t)e * PLANE);
        float ev[4] = {ev4.x, ev4.y, ev4.z, ev4.w};
        float t[4][8];
        #pragma unroll
        for (int r = 0; r < 4; r++){
            float4 l4 = *(const float4*)(Tp + lo[r]);
            float4 o4 = *(const float4*)(Tp + ro[r]);
            t[r][0]=l4.x; t[r][1]=l4.y; t[r][2]=l4.z; t[r][3]=l4.w;
            t[r][4]=o4.x; t[r][5]=o4.y; t[r][6]=o4.z; t[r][7]=o4.w;
        }
        #pragma unroll
        for (int j = 0; j < 4; j++){
            float s =        c[j][0] * t[0][3+j];
            s = fmaf(c[j][1], t[1][4+j], s);
            s = fmaf(c[j][2], t[1][3+j], s);
            s = fmaf(c[j][3], t[0][2+j], s);
            s = fmaf(c[j][4], t[2][4+j], s);
            s = fmaf(c[j][5], t[2][2+j], s);
            s = fmaf(c[j][6], t[0][1+j], s);
            s = fmaf(c[j][7], t[3][4+j], s);
            s = fmaf(c[j][8], t[3][1+j], s);
            acc[j] = fmaf(ev[j], s, acc[j]);
        }
    }

    float part = (csum[0]-acc[0]) + (csum[1]-acc[1]) + (csum[2]-acc[2]) + (csum[3]-acc[3]);

    // block reduction
    for (int s = 32; s; s >>= 1) part += __shfl_xor(part, s);
    __shared__ float sp[8];
    int lane = threadIdx.x & 63, wv = threadIdx.x >> 6;
    if (lane == 0) sp[wv] = part;
    __syncthreads();
    if (threadIdx.x == 0){
        float bs = 0.f;
        for (int v = 0; v < 8; v++) bs += sp[v];
        atomicAdd((double*)(ws + WS_ACC), (double)bs);
    }
}

__global__ void k_final(const float* __restrict__ ws, float* __restrict__ out){
    out[0] = (float)(*(const double*)(ws + WS_ACC) / (double)((size_t)Bb * PLANE));
}

extern "C" void kernel_launch(void* const* d_in, const int* in_sizes, int n_in,
                              void* d_out, int out_size, void* d_ws, size_t ws_size,
                              hipStream_t stream) {
    const float* embeds = (const float*)d_in[0];   // [4,32,512,512]
    const float* tf     = (const float*)d_in[1];   // [4,32,512,512]
    const float* raw    = (const float*)d_in[2];   // [1,1,512,512]
    const float* mask   = (const float*)d_in[3];   // [1,9,512,512]
    float* ws  = (float*)d_ws;
    float* out = (float*)d_out;

    k_init  <<<1, 64, 0, stream>>>(ws);
    k_blur_h<<<PLANE/256, 256, 0, stream>>>(raw, ws);
    k_blur_w<<<PLANE/256, 256, 0, stream>>>(ws);
    k_minmax<<<PLANE/512, 512, 0, stream>>>(ws);
    k_main  <<<PLANE*Bb/4/512, 512, 0, stream>>>(embeds, tf, mask, ws);
    k_final <<<1, 1, 0, stream>>>(ws, out);
}